// Round 3
// baseline (321.094 us; speedup 1.0000x reference)
//
#include <hip/hip_runtime.h>

#define BN 1000000
#define KN 16384
#define HN 64

typedef __bf16 bf16x8 __attribute__((ext_vector_type(8)));
typedef float  f32x4  __attribute__((ext_vector_type(4)));

__device__ __forceinline__ unsigned short f2bf(float f) {
    unsigned u = __float_as_uint(f);
    u += 0x7fffu + ((u >> 16) & 1u);
    return (unsigned short)(u >> 16);
}
__device__ __forceinline__ float bf2f(unsigned short b) {
    return __uint_as_float(((unsigned)b) << 16);
}
__device__ __forceinline__ float silu_f(float v) {
    return v / (1.0f + __expf(-v));
}
__device__ __forceinline__ f32x4 mfma16(bf16x8 a, bf16x8 b, f32x4 c) {
    return __builtin_amdgcn_mfma_f32_16x16x32_bf16(a, b, c, 0, 0, 0);
}

// ---- XLA ErfInv32 polynomial ----
__device__ __forceinline__ float erfinv_xla(float x) {
    float w = -log1pf(-x * x);
    float p;
    if (w < 5.0f) {
        w -= 2.5f;
        p = 2.81022636e-08f;
        p = fmaf(p, w, 3.43273939e-07f);
        p = fmaf(p, w, -3.5233877e-06f);
        p = fmaf(p, w, -4.39150654e-06f);
        p = fmaf(p, w, 0.00021858087f);
        p = fmaf(p, w, -0.00125372503f);
        p = fmaf(p, w, -0.00417768164f);
        p = fmaf(p, w, 0.246640727f);
        p = fmaf(p, w, 1.50140941f);
    } else {
        w = sqrtf(w) - 3.0f;
        p = -0.000200214257f;
        p = fmaf(p, w, 0.000100950558f);
        p = fmaf(p, w, 0.00134934322f);
        p = fmaf(p, w, -0.00367342844f);
        p = fmaf(p, w, 0.00573950773f);
        p = fmaf(p, w, -0.0076224613f);
        p = fmaf(p, w, 0.00943887047f);
        p = fmaf(p, w, 1.00167406f);
        p = fmaf(p, w, 2.83297682f);
    }
    return p * x;
}

// ---- jax.random.normal(key(42), (16384,)), threefry_partitionable: bits = out0^out1 ----
__device__ __forceinline__ float jax_eps16384(int gid) {
    const unsigned k0 = 0u, k1 = 42u, k2 = 0x1BD11BDAu ^ 0u ^ 42u;
    unsigned x0 = 0u + k0;
    unsigned x1 = (unsigned)gid + k1;
#define TF_RND(r) { x0 += x1; x1 = (x1 << (r)) | (x1 >> (32 - (r))); x1 ^= x0; }
    TF_RND(13) TF_RND(15) TF_RND(26) TF_RND(6)  x0 += k1; x1 += k2 + 1u;
    TF_RND(17) TF_RND(29) TF_RND(16) TF_RND(24) x0 += k2; x1 += k0 + 2u;
    TF_RND(13) TF_RND(15) TF_RND(26) TF_RND(6)  x0 += k0; x1 += k1 + 3u;
    TF_RND(17) TF_RND(29) TF_RND(16) TF_RND(24) x0 += k1; x1 += k2 + 4u;
    TF_RND(13) TF_RND(15) TF_RND(26) TF_RND(6)  x0 += k2; x1 += k0 + 5u;
#undef TF_RND
    unsigned bits = x0 ^ x1;
    float f = __uint_as_float((bits >> 9) | 0x3f800000u) - 1.0f;
    const float mn = -0.99999994f;
    float u = fmaxf(f * 2.0f + mn, mn);
    return 1.41421354f * erfinv_xla(u);
}

// ============ counting sort: histogram, prefix, scatter ============
__global__ __launch_bounds__(256) void k_count(const int* __restrict__ gl, int* __restrict__ counts) {
    int i = blockIdx.x * 256 + threadIdx.x;
    if (i < BN) atomicAdd(&counts[gl[i]], 1);
}

__global__ __launch_bounds__(1024) void k_scan(const int* __restrict__ counts, int* __restrict__ cursor) {
    __shared__ int part[1024];
    int t = threadIdx.x;
    int loc[16]; int s = 0;
    #pragma unroll
    for (int i = 0; i < 16; ++i) { loc[i] = s; s += counts[t * 16 + i]; }
    part[t] = s;
    __syncthreads();
    for (int off = 1; off < 1024; off <<= 1) {
        int v = (t >= off) ? part[t - off] : 0;
        __syncthreads();
        part[t] += v;
        __syncthreads();
    }
    int base = (t > 0) ? part[t - 1] : 0;
    #pragma unroll
    for (int i = 0; i < 16; ++i) cursor[t * 16 + i] = base + loc[i];
}

__global__ __launch_bounds__(256) void k_scatter(const int* __restrict__ gl, int* __restrict__ cursor,
                                                 int* __restrict__ sidx, int* __restrict__ sg) {
    int i = blockIdx.x * 256 + threadIdx.x;
    if (i < BN) {
        int g = gl[i];
        int p = atomicAdd(&cursor[g], 1);
        sidx[p] = i;
        sg[p] = g;
    }
}

// ============ phase 1: MLP on group-sorted rows + segmented reduce ============
__global__ __launch_bounds__(256) void k_phase1(
    const float* __restrict__ x, const int* __restrict__ sidx, const int* __restrict__ sg,
    const float* __restrict__ W1, const float* __restrict__ b1,
    const float* __restrict__ W2, const float* __restrict__ b2,
    float* __restrict__ gsum)
{
    __shared__ __align__(16) unsigned short w1t[64 * 64];   // [j][k] bf16, swizzled
    __shared__ __align__(16) unsigned short w2t[64 * 64];
    __shared__ __align__(16) unsigned short xh[4][64 * 64]; // per-wave: x -> h1 -> z
    __shared__ float b1s[64], b2s[64];
    __shared__ int   sidx_s[256], sg_s[256];

    const int t = threadIdx.x;
    const int base = blockIdx.x * 256;

    // stage W1^T, W2^T as bf16 with 16B XOR swizzle
    {
        const float4* W1v = (const float4*)W1;
        const float4* W2v = (const float4*)W2;
        #pragma unroll
        for (int i = 0; i < 4; ++i) {
            int e4 = i * 256 + t;         // element e = k*64 + j
            int k  = e4 >> 4;
            int j0 = (e4 & 15) * 4;
            float4 a = W1v[e4];
            float4 b = W2v[e4];
            float av[4] = {a.x, a.y, a.z, a.w};
            float bv[4] = {b.x, b.y, b.z, b.w};
            #pragma unroll
            for (int c = 0; c < 4; ++c) {
                int j = j0 + c;
                int off = j * 128 + ((2 * k) ^ ((j & 7) << 4));
                *(unsigned short*)((char*)w1t + off) = f2bf(av[c]);
                *(unsigned short*)((char*)w2t + off) = f2bf(bv[c]);
            }
        }
    }
    if (t < 64) { b1s[t] = b1[t]; b2s[t] = b2[t]; }
    {
        int r = base + t;
        sidx_s[t] = (r < BN) ? sidx[r] : -1;
        sg_s[t]   = (r < BN) ? sg[r]   : -1;
    }
    __syncthreads();   // sidx_s needed by all threads in staging

    // stage x rows (gathered via sidx) f32 -> bf16, swizzled
    for (int i = 0; i < 16; ++i) {
        int e4 = i * 256 + t;             // float4 index: 16 per row
        int rr = e4 >> 4;
        int k4 = (e4 & 15) * 4;
        int rid = sidx_s[rr];
        float4 v = make_float4(0.f, 0.f, 0.f, 0.f);
        if (rid >= 0) v = *(const float4*)(x + (size_t)rid * 64 + k4);
        int w = rr >> 6, lr = rr & 63;
        int off = lr * 128 + ((2 * k4) ^ ((lr & 7) << 4));
        ushort4 pk;
        pk.x = f2bf(v.x); pk.y = f2bf(v.y); pk.z = f2bf(v.z); pk.w = f2bf(v.w);
        *(ushort4*)((char*)&xh[w][0] + off) = pk;
    }
    __syncthreads();

    const int wv = t >> 6, lane = t & 63;
    const int lj = lane & 15, lg = lane >> 4;
    unsigned short* myx = &xh[wv][0];

    f32x4 acc[4][4];
    #pragma unroll
    for (int a = 0; a < 4; ++a)
        #pragma unroll
        for (int b = 0; b < 4; ++b) acc[a][b] = f32x4{0.f, 0.f, 0.f, 0.f};

    // ---- layer 1: h1 = silu(x @ W1 + b1) ----
    #pragma unroll
    for (int kk = 0; kk < 2; ++kk) {
        const int kbyte = kk * 64 + lg * 16;
        bf16x8 bw[4];
        #pragma unroll
        for (int ct = 0; ct < 4; ++ct) {
            int row = ct * 16 + lj;
            bw[ct] = *(const bf16x8*)((char*)w1t + row * 128 + (kbyte ^ ((row & 7) << 4)));
        }
        #pragma unroll
        for (int rt = 0; rt < 4; ++rt) {
            int row = rt * 16 + lj;
            bf16x8 aw = *(const bf16x8*)((char*)myx + row * 128 + (kbyte ^ ((row & 7) << 4)));
            #pragma unroll
            for (int ct = 0; ct < 4; ++ct)
                acc[rt][ct] = mfma16(aw, bw[ct], acc[rt][ct]);
        }
    }
    {   // epilogue 1: bias+silu -> bf16 -> own LDS region
        float bc[4];
        #pragma unroll
        for (int ct = 0; ct < 4; ++ct) bc[ct] = b1s[ct * 16 + lj];
        #pragma unroll
        for (int rt = 0; rt < 4; ++rt) {
            #pragma unroll
            for (int ct = 0; ct < 4; ++ct) {
                f32x4 v = acc[rt][ct];
                #pragma unroll
                for (int rg = 0; rg < 4; ++rg) {
                    int row = rt * 16 + lg * 4 + rg;
                    int col = ct * 16 + lj;
                    float h = silu_f(v[rg] + bc[ct]);
                    int off = row * 128 + ((2 * col) ^ ((row & 7) << 4));
                    *(unsigned short*)((char*)myx + off) = f2bf(h);
                }
                acc[rt][ct] = f32x4{0.f, 0.f, 0.f, 0.f};
            }
        }
    }
    __syncthreads();

    // ---- layer 2: z = silu(h1 @ W2 + b2) ----
    #pragma unroll
    for (int kk = 0; kk < 2; ++kk) {
        const int kbyte = kk * 64 + lg * 16;
        bf16x8 bw[4];
        #pragma unroll
        for (int ct = 0; ct < 4; ++ct) {
            int row = ct * 16 + lj;
            bw[ct] = *(const bf16x8*)((char*)w2t + row * 128 + (kbyte ^ ((row & 7) << 4)));
        }
        #pragma unroll
        for (int rt = 0; rt < 4; ++rt) {
            int row = rt * 16 + lj;
            bf16x8 aw = *(const bf16x8*)((char*)myx + row * 128 + (kbyte ^ ((row & 7) << 4)));
            #pragma unroll
            for (int ct = 0; ct < 4; ++ct)
                acc[rt][ct] = mfma16(aw, bw[ct], acc[rt][ct]);
        }
    }
    {   // epilogue 2: bias+silu -> bf16 z into own LDS region (overwrites h1)
        float bc[4];
        #pragma unroll
        for (int ct = 0; ct < 4; ++ct) bc[ct] = b2s[ct * 16 + lj];
        #pragma unroll
        for (int rt = 0; rt < 4; ++rt) {
            #pragma unroll
            for (int ct = 0; ct < 4; ++ct) {
                f32x4 v = acc[rt][ct];
                #pragma unroll
                for (int rg = 0; rg < 4; ++rg) {
                    int row = rt * 16 + lg * 4 + rg;
                    int col = ct * 16 + lj;
                    float z = silu_f(v[rg] + bc[ct]);
                    int off = row * 128 + ((2 * col) ^ ((row & 7) << 4));
                    *(unsigned short*)((char*)myx + off) = f2bf(z);
                }
            }
        }
    }
    __syncthreads();

    // ---- segmented reduce: thread t scans col (t&63) over its wave's 64 sorted rows ----
    {
        const int c  = t & 63;
        const int ch = t >> 6;
        const unsigned short* zreg = &xh[ch][0];
        float vsum = 0.0f;
        int curg = sg_s[ch * 64];
        for (int row = 0; row < 64; ++row) {
            int g = sg_s[ch * 64 + row];
            unsigned short zb = *(const unsigned short*)((const char*)zreg + row * 128 + ((2 * c) ^ ((row & 7) << 4)));
            float zv = bf2f(zb);
            if (g != curg) {
                if (curg >= 0) atomicAdd(&gsum[curg * 64 + c], vsum);
                vsum = 0.0f;
                curg = g;
            }
            vsum += zv;
        }
        if (curg >= 0) atomicAdd(&gsum[curg * 64 + c], vsum);
    }
}

// ============ phase 2: group head + reparam sample ============
__global__ __launch_bounds__(64) void k_phase2(
    const float* __restrict__ gsum, const int* __restrict__ counts,
    const float* __restrict__ W3, const float* __restrict__ b3,
    const float* __restrict__ wmu, const float* __restrict__ bmu,
    const float* __restrict__ wlv, const float* __restrict__ blv,
    float* __restrict__ out, float* __restrict__ taug, float* __restrict__ ltaug)
{
    __shared__ __align__(16) float w3t[64 * 64];   // [j][k]
    __shared__ float b3s[64], wmus[64], wlvs[64];
    const int t = threadIdx.x;
    for (int i = 0; i < 64; ++i) w3t[t * 64 + i] = W3[i * 64 + t];
    b3s[t] = b3[t]; wmus[t] = wmu[t]; wlvs[t] = wlv[t];
    __syncthreads();

    const int gid = blockIdx.x * 64 + t;
    const float inv = 1.0f / (float)counts[gid];
    float gf[64];
    #pragma unroll
    for (int i = 0; i < 16; ++i) {
        float4 v = *(const float4*)(gsum + (size_t)gid * 64 + i * 4);
        gf[i * 4 + 0] = v.x * inv; gf[i * 4 + 1] = v.y * inv;
        gf[i * 4 + 2] = v.z * inv; gf[i * 4 + 3] = v.w * inv;
    }
    float mu = bmu[0], lv = blv[0];
    for (int j = 0; j < 64; ++j) {
        float a = b3s[j];
        const float4* wr = (const float4*)(w3t + j * 64);
        #pragma unroll
        for (int k = 0; k < 16; ++k) {
            float4 wv = wr[k];
            a += gf[k * 4 + 0] * wv.x + gf[k * 4 + 1] * wv.y
               + gf[k * 4 + 2] * wv.z + gf[k * 4 + 3] * wv.w;
        }
        float h = silu_f(a);
        mu += h * wmus[j];
        lv += h * wlvs[j];
    }
    lv = fminf(fmaxf(lv, -10.0f), 4.0f);
    float sd  = __expf(0.5f * lv);
    float eps = jax_eps16384(gid);
    float lt  = mu + sd * eps;
    out[gid]      = mu;
    out[KN + gid] = lv;
    taug[gid]  = __expf(lt);
    ltaug[gid] = lt;
}

// ============ phase 3: broadcast per-group sample to reflections ============
__global__ __launch_bounds__(256) void k_phase3(
    const int* __restrict__ gl, const float* __restrict__ taug,
    const float* __restrict__ ltaug, float* __restrict__ out)
{
    int i = blockIdx.x * 256 + threadIdx.x;
    if (i < BN) {
        int g = gl[i];
        out[2 * KN + i]      = taug[g];
        out[2 * KN + BN + i] = ltaug[g];
    }
}

extern "C" void kernel_launch(void* const* d_in, const int* in_sizes, int n_in,
                              void* d_out, int out_size, void* d_ws, size_t ws_size,
                              hipStream_t stream)
{
    const float* x   = (const float*)d_in[0];
    const int*   gl  = (const int*)d_in[1];
    const float* W1  = (const float*)d_in[2];
    const float* b1  = (const float*)d_in[3];
    const float* W2  = (const float*)d_in[4];
    const float* b2  = (const float*)d_in[5];
    const float* W3  = (const float*)d_in[6];
    const float* b3  = (const float*)d_in[7];
    const float* wmu = (const float*)d_in[8];
    const float* bmu = (const float*)d_in[9];
    const float* wlv = (const float*)d_in[10];
    const float* blv = (const float*)d_in[11];
    float* out = (float*)d_out;

    float* ws     = (float*)d_ws;
    float* gsum   = ws;                          // KN*HN f32
    int*   counts = (int*)(gsum + KN * HN);      // KN
    int*   cursor = counts + KN;                 // KN
    float* taug   = (float*)(cursor + KN);       // KN
    float* ltaug  = taug + KN;                   // KN
    int*   sidx   = (int*)(ltaug + KN);          // BN
    int*   sg     = sidx + BN;                   // BN

    hipMemsetAsync(gsum, 0, (size_t)KN * HN * sizeof(float), stream);
    hipMemsetAsync(counts, 0, (size_t)KN * sizeof(int), stream);

    const int nb = (BN + 255) / 256;
    k_count  <<<nb, 256, 0, stream>>>(gl, counts);
    k_scan   <<<1, 1024, 0, stream>>>(counts, cursor);
    k_scatter<<<nb, 256, 0, stream>>>(gl, cursor, sidx, sg);
    k_phase1 <<<nb, 256, 0, stream>>>(x, sidx, sg, W1, b1, W2, b2, gsum);
    k_phase2 <<<KN / 64, 64, 0, stream>>>(gsum, counts, W3, b3, wmu, bmu, wlv, blv, out, taug, ltaug);
    k_phase3 <<<nb, 256, 0, stream>>>(gl, taug, ltaug, out);
}

// Round 4
// 241.919 us; speedup vs baseline: 1.3273x; 1.3273x over previous
//
#include <hip/hip_runtime.h>

#define BN 1000000
#define KN 16384
#define HN 64

typedef __bf16 bf16x8 __attribute__((ext_vector_type(8)));
typedef float  f32x4  __attribute__((ext_vector_type(4)));
typedef unsigned short u16x8 __attribute__((ext_vector_type(8)));

__device__ __forceinline__ unsigned short f2bf(float f) {
    unsigned u = __float_as_uint(f);
    u += 0x7fffu + ((u >> 16) & 1u);
    return (unsigned short)(u >> 16);
}
__device__ __forceinline__ float bf2f(unsigned short b) {
    return __uint_as_float(((unsigned)b) << 16);
}
__device__ __forceinline__ float silu_f(float v) {
    // v * rcp(1+e^-v): v_rcp_f32 approx (~1e-6 rel) is well inside the 5x absmax margin
    return v * __builtin_amdgcn_rcpf(1.0f + __expf(-v));
}
__device__ __forceinline__ f32x4 mfma16(bf16x8 a, bf16x8 b, f32x4 c) {
    return __builtin_amdgcn_mfma_f32_16x16x32_bf16(a, b, c, 0, 0, 0);
}

// ---- XLA ErfInv32 polynomial ----
__device__ __forceinline__ float erfinv_xla(float x) {
    float w = -log1pf(-x * x);
    float p;
    if (w < 5.0f) {
        w -= 2.5f;
        p = 2.81022636e-08f;
        p = fmaf(p, w, 3.43273939e-07f);
        p = fmaf(p, w, -3.5233877e-06f);
        p = fmaf(p, w, -4.39150654e-06f);
        p = fmaf(p, w, 0.00021858087f);
        p = fmaf(p, w, -0.00125372503f);
        p = fmaf(p, w, -0.00417768164f);
        p = fmaf(p, w, 0.246640727f);
        p = fmaf(p, w, 1.50140941f);
    } else {
        w = sqrtf(w) - 3.0f;
        p = -0.000200214257f;
        p = fmaf(p, w, 0.000100950558f);
        p = fmaf(p, w, 0.00134934322f);
        p = fmaf(p, w, -0.00367342844f);
        p = fmaf(p, w, 0.00573950773f);
        p = fmaf(p, w, -0.0076224613f);
        p = fmaf(p, w, 0.00943887047f);
        p = fmaf(p, w, 1.00167406f);
        p = fmaf(p, w, 2.83297682f);
    }
    return p * x;
}

// ---- jax.random.normal(key(42), (16384,)), threefry_partitionable: bits = out0^out1 ----
__device__ __forceinline__ float jax_eps16384(int gid) {
    const unsigned k0 = 0u, k1 = 42u, k2 = 0x1BD11BDAu ^ 0u ^ 42u;
    unsigned x0 = 0u + k0;
    unsigned x1 = (unsigned)gid + k1;
#define TF_RND(r) { x0 += x1; x1 = (x1 << (r)) | (x1 >> (32 - (r))); x1 ^= x0; }
    TF_RND(13) TF_RND(15) TF_RND(26) TF_RND(6)  x0 += k1; x1 += k2 + 1u;
    TF_RND(17) TF_RND(29) TF_RND(16) TF_RND(24) x0 += k2; x1 += k0 + 2u;
    TF_RND(13) TF_RND(15) TF_RND(26) TF_RND(6)  x0 += k0; x1 += k1 + 3u;
    TF_RND(17) TF_RND(29) TF_RND(16) TF_RND(24) x0 += k1; x1 += k2 + 4u;
    TF_RND(13) TF_RND(15) TF_RND(26) TF_RND(6)  x0 += k2; x1 += k0 + 5u;
#undef TF_RND
    unsigned bits = x0 ^ x1;
    float f = __uint_as_float((bits >> 9) | 0x3f800000u) - 1.0f;
    const float mn = -0.99999994f;
    float u = fmaxf(f * 2.0f + mn, mn);
    return 1.41421354f * erfinv_xla(u);
}

// ============ counting sort: histogram, prefix, scatter ============
__global__ __launch_bounds__(256) void k_count(const int* __restrict__ gl, int* __restrict__ counts) {
    int i = blockIdx.x * 256 + threadIdx.x;
    if (i < BN) atomicAdd(&counts[gl[i]], 1);
}

__global__ __launch_bounds__(1024) void k_scan(const int* __restrict__ counts, int* __restrict__ cursor) {
    __shared__ int part[1024];
    int t = threadIdx.x;
    int loc[16]; int s = 0;
    #pragma unroll
    for (int i = 0; i < 16; ++i) { loc[i] = s; s += counts[t * 16 + i]; }
    part[t] = s;
    __syncthreads();
    for (int off = 1; off < 1024; off <<= 1) {
        int v = (t >= off) ? part[t - off] : 0;
        __syncthreads();
        part[t] += v;
        __syncthreads();
    }
    int base = (t > 0) ? part[t - 1] : 0;
    #pragma unroll
    for (int i = 0; i < 16; ++i) cursor[t * 16 + i] = base + loc[i];
}

__global__ __launch_bounds__(256) void k_scatter(const int* __restrict__ gl, int* __restrict__ cursor,
                                                 int2* __restrict__ spk) {
    int i = blockIdx.x * 256 + threadIdx.x;
    if (i < BN) {
        int g = gl[i];
        int p = atomicAdd(&cursor[g], 1);
        spk[p] = make_int2(i, g);   // single 8B scattered store
    }
}

// ============ phase 1: MLP on group-sorted rows + segmented reduce ============
__global__ __launch_bounds__(256) void k_phase1(
    const float* __restrict__ x, const int2* __restrict__ spk,
    const float* __restrict__ W1, const float* __restrict__ b1,
    const float* __restrict__ W2, const float* __restrict__ b2,
    float* __restrict__ gsum)
{
    __shared__ __align__(16) unsigned short w1t[64 * 64];   // [j][k] bf16, swizzled
    __shared__ __align__(16) unsigned short w2t[64 * 64];
    __shared__ __align__(16) unsigned short xh[4][64 * 64]; // per-wave: x -> h1 -> zT
    __shared__ float b1s[64], b2s[64];
    __shared__ __align__(16) int sg_s[256];

    const int t = threadIdx.x;
    const int base = blockIdx.x * 256;
    const int t4 = t >> 4;            // 0..15: row-within-16 for staging
    const int kc = (t & 15) * 4;      // float col for staging

    // ---- half 0: issue row-id loads + x gathers ----
    int   rid0[8];
    float4 xv0[8];
    #pragma unroll
    for (int i = 0; i < 8; ++i) {
        int r = base + i * 16 + t4;
        rid0[i] = (r < BN) ? spk[r].x : -1;
    }
    #pragma unroll
    for (int i = 0; i < 8; ++i)
        xv0[i] = (rid0[i] >= 0) ? *(const float4*)(x + (size_t)rid0[i] * 64 + kc)
                                : make_float4(0.f, 0.f, 0.f, 0.f);

    // ---- W staging (L1/L2-hot loads + VALU) overlaps the gather flight ----
    {
        const float4* W1v = (const float4*)W1;
        const float4* W2v = (const float4*)W2;
        #pragma unroll
        for (int i = 0; i < 4; ++i) {
            int e4 = i * 256 + t;         // element e = k*64 + j
            int k  = e4 >> 4;
            int j0 = (e4 & 15) * 4;
            float4 a = W1v[e4];
            float4 b = W2v[e4];
            float av[4] = {a.x, a.y, a.z, a.w};
            float bv[4] = {b.x, b.y, b.z, b.w};
            #pragma unroll
            for (int c = 0; c < 4; ++c) {
                int j = j0 + c;
                int off = j * 128 + ((2 * k) ^ ((j & 7) << 4));
                *(unsigned short*)((char*)w1t + off) = f2bf(av[c]);
                *(unsigned short*)((char*)w2t + off) = f2bf(bv[c]);
            }
        }
    }

    // ---- convert/write half 0 ----
    #pragma unroll
    for (int i = 0; i < 8; ++i) {
        int rr = i * 16 + t4;
        int w = rr >> 6, lr = rr & 63;
        int off = lr * 128 + ((2 * kc) ^ ((lr & 7) << 4));
        ushort4 pk;
        pk.x = f2bf(xv0[i].x); pk.y = f2bf(xv0[i].y);
        pk.z = f2bf(xv0[i].z); pk.w = f2bf(xv0[i].w);
        *(ushort4*)((char*)&xh[w][0] + off) = pk;
    }

    // ---- half 1: issue loads, overlap with bias/sg staging ----
    int   rid1[8];
    float4 xv1[8];
    #pragma unroll
    for (int i = 0; i < 8; ++i) {
        int r = base + (8 + i) * 16 + t4;
        rid1[i] = (r < BN) ? spk[r].x : -1;
    }
    #pragma unroll
    for (int i = 0; i < 8; ++i)
        xv1[i] = (rid1[i] >= 0) ? *(const float4*)(x + (size_t)rid1[i] * 64 + kc)
                                : make_float4(0.f, 0.f, 0.f, 0.f);

    if (t < 64) { b1s[t] = b1[t]; b2s[t] = b2[t]; }
    {
        int r = base + t;
        sg_s[t] = (r < BN) ? spk[r].y : -1;
    }

    #pragma unroll
    for (int i = 0; i < 8; ++i) {
        int rr = (8 + i) * 16 + t4;
        int w = rr >> 6, lr = rr & 63;
        int off = lr * 128 + ((2 * kc) ^ ((lr & 7) << 4));
        ushort4 pk;
        pk.x = f2bf(xv1[i].x); pk.y = f2bf(xv1[i].y);
        pk.z = f2bf(xv1[i].z); pk.w = f2bf(xv1[i].w);
        *(ushort4*)((char*)&xh[w][0] + off) = pk;
    }
    __syncthreads();

    const int wv = t >> 6, lane = t & 63;
    const int lj = lane & 15, lg = lane >> 4;
    unsigned short* myx = &xh[wv][0];

    f32x4 acc[4][4];
    #pragma unroll
    for (int a = 0; a < 4; ++a)
        #pragma unroll
        for (int b = 0; b < 4; ++b) acc[a][b] = f32x4{0.f, 0.f, 0.f, 0.f};

    // ---- layer 1: h1 = silu(x @ W1 + b1) ----
    #pragma unroll
    for (int kk = 0; kk < 2; ++kk) {
        const int kbyte = kk * 64 + lg * 16;
        bf16x8 bw[4];
        #pragma unroll
        for (int ct = 0; ct < 4; ++ct) {
            int row = ct * 16 + lj;
            bw[ct] = *(const bf16x8*)((char*)w1t + row * 128 + (kbyte ^ ((row & 7) << 4)));
        }
        #pragma unroll
        for (int rt = 0; rt < 4; ++rt) {
            int row = rt * 16 + lj;
            bf16x8 aw = *(const bf16x8*)((char*)myx + row * 128 + (kbyte ^ ((row & 7) << 4)));
            #pragma unroll
            for (int ct = 0; ct < 4; ++ct)
                acc[rt][ct] = mfma16(aw, bw[ct], acc[rt][ct]);
        }
    }
    {   // epilogue 1: bias+silu -> bf16 -> own LDS region (row-major, A-operand layout)
        float bc[4];
        #pragma unroll
        for (int ct = 0; ct < 4; ++ct) bc[ct] = b1s[ct * 16 + lj];
        #pragma unroll
        for (int rt = 0; rt < 4; ++rt) {
            #pragma unroll
            for (int ct = 0; ct < 4; ++ct) {
                f32x4 v = acc[rt][ct];
                #pragma unroll
                for (int rg = 0; rg < 4; ++rg) {
                    int row = rt * 16 + lg * 4 + rg;
                    int col = ct * 16 + lj;
                    float h = silu_f(v[rg] + bc[ct]);
                    int off = row * 128 + ((2 * col) ^ ((row & 7) << 4));
                    *(unsigned short*)((char*)myx + off) = f2bf(h);
                }
                acc[rt][ct] = f32x4{0.f, 0.f, 0.f, 0.f};
            }
        }
    }
    __syncthreads();

    // ---- layer 2: z = silu(h1 @ W2 + b2) ----
    #pragma unroll
    for (int kk = 0; kk < 2; ++kk) {
        const int kbyte = kk * 64 + lg * 16;
        bf16x8 bw[4];
        #pragma unroll
        for (int ct = 0; ct < 4; ++ct) {
            int row = ct * 16 + lj;
            bw[ct] = *(const bf16x8*)((char*)w2t + row * 128 + (kbyte ^ ((row & 7) << 4)));
        }
        #pragma unroll
        for (int rt = 0; rt < 4; ++rt) {
            int row = rt * 16 + lj;
            bf16x8 aw = *(const bf16x8*)((char*)myx + row * 128 + (kbyte ^ ((row & 7) << 4)));
            #pragma unroll
            for (int ct = 0; ct < 4; ++ct)
                acc[rt][ct] = mfma16(aw, bw[ct], acc[rt][ct]);
        }
    }
    {   // epilogue 2: bias+silu -> z TRANSPOSED in LDS: zT[col][row], packed ushort4 stores
        float bc[4];
        #pragma unroll
        for (int ct = 0; ct < 4; ++ct) bc[ct] = b2s[ct * 16 + lj];
        #pragma unroll
        for (int rt = 0; rt < 4; ++rt) {
            #pragma unroll
            for (int ct = 0; ct < 4; ++ct) {
                f32x4 v = acc[rt][ct];
                int col  = ct * 16 + lj;
                int row0 = rt * 16 + lg * 4;
                ushort4 pk;
                pk.x = f2bf(silu_f(v[0] + bc[ct]));
                pk.y = f2bf(silu_f(v[1] + bc[ct]));
                pk.z = f2bf(silu_f(v[2] + bc[ct]));
                pk.w = f2bf(silu_f(v[3] + bc[ct]));
                *(ushort4*)((char*)myx + col * 128 + ((2 * row0) ^ ((col & 7) << 4))) = pk;
            }
        }
    }
    // no barrier: reduce reads only this wave's own region; DS ops are in-order per wave

    // ---- segmented reduce: thread t owns col (t&63); 8 rows per ds_read_b128 ----
    {
        const int c  = t & 63;
        const int ch = t >> 6;
        const char* zT = (const char*)&xh[ch][0];
        float vsum = 0.0f;
        int curg = -2;
        #pragma unroll
        for (int blk = 0; blk < 8; ++blk) {
            u16x8 v = *(const u16x8*)(zT + c * 128 + ((16 * blk) ^ ((c & 7) << 4)));
            int4 ga = *(const int4*)(&sg_s[ch * 64 + blk * 8]);
            int4 gb = *(const int4*)(&sg_s[ch * 64 + blk * 8 + 4]);
            int gs[8] = {ga.x, ga.y, ga.z, ga.w, gb.x, gb.y, gb.z, gb.w};
            #pragma unroll
            for (int j = 0; j < 8; ++j) {
                int g = gs[j];
                if (g != curg) {
                    if (curg >= 0) atomicAdd(&gsum[curg * 64 + c], vsum);
                    vsum = 0.0f;
                    curg = g;
                }
                vsum += bf2f(v[j]);
            }
        }
        if (curg >= 0) atomicAdd(&gsum[curg * 64 + c], vsum);
    }
}

// ============ phase 2: group head + reparam sample ============
__global__ __launch_bounds__(64) void k_phase2(
    const float* __restrict__ gsum, const int* __restrict__ counts,
    const float* __restrict__ W3, const float* __restrict__ b3,
    const float* __restrict__ wmu, const float* __restrict__ bmu,
    const float* __restrict__ wlv, const float* __restrict__ blv,
    float* __restrict__ out, float* __restrict__ taug, float* __restrict__ ltaug)
{
    __shared__ __align__(16) float w3t[64 * 64];   // [j][k]
    __shared__ float b3s[64], wmus[64], wlvs[64];
    const int t = threadIdx.x;
    for (int i = 0; i < 64; ++i) w3t[t * 64 + i] = W3[i * 64 + t];
    b3s[t] = b3[t]; wmus[t] = wmu[t]; wlvs[t] = wlv[t];
    __syncthreads();

    const int gid = blockIdx.x * 64 + t;
    const float inv = 1.0f / (float)counts[gid];
    float gf[64];
    #pragma unroll
    for (int i = 0; i < 16; ++i) {
        float4 v = *(const float4*)(gsum + (size_t)gid * 64 + i * 4);
        gf[i * 4 + 0] = v.x * inv; gf[i * 4 + 1] = v.y * inv;
        gf[i * 4 + 2] = v.z * inv; gf[i * 4 + 3] = v.w * inv;
    }
    float mu = bmu[0], lv = blv[0];
    for (int j = 0; j < 64; ++j) {
        float a = b3s[j];
        const float4* wr = (const float4*)(w3t + j * 64);
        #pragma unroll
        for (int k = 0; k < 16; ++k) {
            float4 wv = wr[k];
            a += gf[k * 4 + 0] * wv.x + gf[k * 4 + 1] * wv.y
               + gf[k * 4 + 2] * wv.z + gf[k * 4 + 3] * wv.w;
        }
        float h = silu_f(a);
        mu += h * wmus[j];
        lv += h * wlvs[j];
    }
    lv = fminf(fmaxf(lv, -10.0f), 4.0f);
    float sd  = __expf(0.5f * lv);
    float eps = jax_eps16384(gid);
    float lt  = mu + sd * eps;
    out[gid]      = mu;
    out[KN + gid] = lv;
    taug[gid]  = __expf(lt);
    ltaug[gid] = lt;
}

// ============ phase 3: broadcast per-group sample to reflections ============
__global__ __launch_bounds__(256) void k_phase3(
    const int* __restrict__ gl, const float* __restrict__ taug,
    const float* __restrict__ ltaug, float* __restrict__ out)
{
    int i = blockIdx.x * 256 + threadIdx.x;
    if (i < BN) {
        int g = gl[i];
        out[2 * KN + i]      = taug[g];
        out[2 * KN + BN + i] = ltaug[g];
    }
}

extern "C" void kernel_launch(void* const* d_in, const int* in_sizes, int n_in,
                              void* d_out, int out_size, void* d_ws, size_t ws_size,
                              hipStream_t stream)
{
    const float* x   = (const float*)d_in[0];
    const int*   gl  = (const int*)d_in[1];
    const float* W1  = (const float*)d_in[2];
    const float* b1  = (const float*)d_in[3];
    const float* W2  = (const float*)d_in[4];
    const float* b2  = (const float*)d_in[5];
    const float* W3  = (const float*)d_in[6];
    const float* b3  = (const float*)d_in[7];
    const float* wmu = (const float*)d_in[8];
    const float* bmu = (const float*)d_in[9];
    const float* wlv = (const float*)d_in[10];
    const float* blv = (const float*)d_in[11];
    float* out = (float*)d_out;

    float* ws     = (float*)d_ws;
    float* gsum   = ws;                          // KN*HN f32
    int*   counts = (int*)(gsum + KN * HN);      // KN
    int*   cursor = counts + KN;                 // KN
    float* taug   = (float*)(cursor + KN);       // KN
    float* ltaug  = taug + KN;                   // KN
    int2*  spk    = (int2*)(ltaug + KN);         // BN int2 (sorted: .x=orig row, .y=group)

    hipMemsetAsync(gsum, 0, (size_t)KN * HN * sizeof(float), stream);
    hipMemsetAsync(counts, 0, (size_t)KN * sizeof(int), stream);

    const int nb = (BN + 255) / 256;
    k_count  <<<nb, 256, 0, stream>>>(gl, counts);
    k_scan   <<<1, 1024, 0, stream>>>(counts, cursor);
    k_scatter<<<nb, 256, 0, stream>>>(gl, cursor, spk);
    k_phase1 <<<nb, 256, 0, stream>>>(x, spk, W1, b1, W2, b2, gsum);
    k_phase2 <<<KN / 64, 64, 0, stream>>>(gsum, counts, W3, b3, wmu, bmu, wlv, blv, out, taug, ltaug);
    k_phase3 <<<nb, 256, 0, stream>>>(gl, taug, ltaug, out);
}